// Round 11
// baseline (186.362 us; speedup 1.0000x reference)
//
#include <hip/hip_runtime.h>
#include <math.h>

#define EPSF 1e-6f
#define NUM_V 10
#define W_IMG 2000
#define H_IMG 1500
#define HW_IMG (W_IMG * H_IMG)
#define TH_QUAD (H_IMG - 1)      // quad-origin rows (y0 <= H-2 always)
#define SAMPLE_BLOCKS 2048       // 8192 waves
#define MAX_CHUNKS 80            // ceil(1000*10/128)=79, margin
#define NDESC 3                  // descriptors per loop iteration (12 gathers in flight)

__device__ __forceinline__ void cross3(const float a[3], const float b[3], float c[3]) {
    c[0] = a[1] * b[2] - a[2] * b[1];
    c[1] = a[2] * b[0] - a[0] * b[2];
    c[2] = a[0] * b[1] - a[1] * b[0];
}
__device__ __forceinline__ float dot3(const float a[3], const float b[3]) {
    return a[0] * b[0] + a[1] * b[1] + a[2] * b[2];
}
__device__ __forceinline__ float norm3(const float a[3]) {
    return sqrtf(a[0] * a[0] + a[1] * a[1] + a[2] * a[2]);
}

// ---- T = K2h @ E2 @ inv(E1), one thread ----
__device__ void do_init(const float* __restrict__ K2, const float* __restrict__ E1,
                        const float* __restrict__ E2, float* __restrict__ T) {
    double M[4][8];
    for (int i = 0; i < 4; ++i)
        for (int j = 0; j < 4; ++j) {
            M[i][j] = (double)E1[i * 4 + j];
            M[i][j + 4] = (i == j) ? 1.0 : 0.0;
        }
    for (int col = 0; col < 4; ++col) {
        int piv = col;
        double best = fabs(M[col][col]);
        for (int r = col + 1; r < 4; ++r) {
            double v = fabs(M[r][col]);
            if (v > best) { best = v; piv = r; }
        }
        if (piv != col)
            for (int j = 0; j < 8; ++j) {
                double t = M[col][j]; M[col][j] = M[piv][j]; M[piv][j] = t;
            }
        double d = M[col][col];
        for (int j = 0; j < 8; ++j) M[col][j] /= d;
        for (int r = 0; r < 4; ++r) {
            if (r == col) continue;
            double f = M[r][col];
            for (int j = 0; j < 8; ++j) M[r][j] -= f * M[col][j];
        }
    }
    double E[4][4];
    for (int i = 0; i < 4; ++i)
        for (int j = 0; j < 4; ++j) {
            double s = 0.0;
            for (int k = 0; k < 4; ++k) s += (double)E2[i * 4 + k] * M[k][j + 4];
            E[i][j] = s;
        }
    for (int i = 0; i < 4; ++i)
        for (int j = 0; j < 4; ++j) {
            double s = 0.0;
            if (i < 3) {
                for (int k = 0; k < 3; ++k) s += (double)K2[i * 3 + k] * E[k][j];
            } else {
                s = E[3][j];
            }
            T[i * 4 + j] = (float)s;
        }
}

// ---- geom: thread per edge; chunk counts; wave-partial losses ----
__global__ __launch_bounds__(256) void geom_kernel(const float* __restrict__ ep, int N,
                                                   float4* __restrict__ geo,
                                                   int* __restrict__ nwv,
                                                   double* __restrict__ gnl,
                                                   double* __restrict__ gzl,
                                                   double* __restrict__ gcnt) {
    const int e = blockIdx.x * 256 + threadIdx.x;
    float nl = 0.f, zl = 0.f;
    int cn = 0;
    if (e < N) {
        const float4* P4 = (const float4*)(ep + (size_t)e * 12);
        float4 a4 = P4[0], b4 = P4[1], c4 = P4[2];
        float p0[3] = {a4.x, a4.y, a4.z};
        float p1[3] = {a4.w, b4.x, b4.y};
        float p2[3] = {b4.z, b4.w, c4.x};
        float p3[3] = {c4.y, c4.z, c4.w};
        float cd[3] = {p1[0] - p0[0], p1[1] - p0[1], p1[2] - p0[2]};
        float nd[3] = {p3[0] - p1[0], p3[1] - p1[1], p3[2] - p1[2]};
        float pd[3] = {p0[0] - p2[0], p0[1] - p2[1], p0[2] - p2[2]};
        float ce[3] = {cd[0] + EPSF, cd[1] + EPSF, cd[2] + EPSF};
        float clen = norm3(ce);
        float dir[3] = {cd[0] / clen, cd[1] / clen, cd[2] / clen};
        float cnv[3];
        cross3(dir, nd, cnv);
        float n1 = norm3(cnv) + EPSF;
        cnv[0] /= n1; cnv[1] /= n1; cnv[2] /= n1;
        if (cnv[2] > 0.f) { cnv[0] = -cnv[0]; cnv[1] = -cnv[1]; cnv[2] = -cnv[2]; }
        float up[3];
        cross3(cnv, dir, up);
        float n2 = norm3(up) + EPSF;
        up[0] /= n2; up[1] /= n2; up[2] /= n2;
        float pn[3];
        cross3(pd, dir, pn);
        float n3 = norm3(pn) + EPSF;
        pn[0] /= n3; pn[1] /= n3; pn[2] /= n3;
        float obs[3];
        cross3(p0, p1, obs);
        float n4 = norm3(obs) + EPSF;
        obs[0] /= n4; obs[1] /= n4; obs[2] /= n4;
        int nh = (int)floorf(clen / 0.05f);
        nh = max(2, min(1000, nh));
        nl = 1.f - dot3(cnv, pn);
        float snp = fminf(fabsf(dot3(up, obs)), 0.5f);
        zl = 1.f - snp * 2.f;
        int nsamp = nh * NUM_V;
        cn = nsamp;
        geo[3 * e + 0] = make_float4(p0[0], p0[1], p0[2], clen);
        geo[3 * e + 1] = make_float4(dir[0], dir[1], dir[2], (float)(nh - 1));
        geo[3 * e + 2] = make_float4(up[0], up[1], up[2], __int_as_float(nsamp));
        nwv[e] = (nsamp + 127) / 128;  // 128-sample chunks
    }
#pragma unroll
    for (int off = 32; off > 0; off >>= 1) {
        nl += __shfl_down(nl, off);
        zl += __shfl_down(zl, off);
        cn += __shfl_down(cn, off);
    }
    if ((threadIdx.x & 63) == 0) {
        const int w = blockIdx.x * 4 + (threadIdx.x >> 6);
        gnl[w] = (double)nl;
        gzl[w] = (double)zl;
        gcnt[w] = (double)cn;
    }
}

// ---- sched(+scan fused): block redundantly sums base prefix, scans locally, scatters ----
__global__ __launch_bounds__(256) void sched_scan_kernel(
    const int* __restrict__ nwv, int N, unsigned* __restrict__ sched, int* __restrict__ total,
    const float* __restrict__ K2, const float* __restrict__ E1, const float* __restrict__ E2,
    float* __restrict__ T) {
    __shared__ int s_red[256];
    const int b = blockIdx.x;
    const int tid = threadIdx.x;
    if (b == 0 && tid == 0) do_init(K2, E1, E2, T);
    const int lo = b * 256;
    int acc = 0;
    for (int i = tid; i < lo; i += 256) acc += nwv[i];
    s_red[tid] = acc;
    __syncthreads();
    for (int off = 128; off > 0; off >>= 1) {
        if (tid < off) s_red[tid] += s_red[tid + off];
        __syncthreads();
    }
    const int base0 = s_red[0];
    __syncthreads();
    const int e = lo + tid;
    const int mine = (e < N) ? nwv[e] : 0;
    s_red[tid] = mine;
    __syncthreads();
    for (int off = 1; off < 256; off <<= 1) {
        int v = (tid >= off) ? s_red[tid - off] : 0;
        __syncthreads();
        s_red[tid] += v;
        __syncthreads();
    }
    if (e < N) {
        int basee = base0 + (s_red[tid] - mine);
        const unsigned tag = ((unsigned)e) << 8;
        for (int j = 0; j < mine; ++j) sched[basee + j] = tag | (unsigned)j;
    }
    if (b == (int)gridDim.x - 1 && tid == 255) *total = base0 + s_red[255];
}

__device__ __forceinline__ unsigned quant565(float r, float g, float b) {
    unsigned r5 = (unsigned)fmaf(r, 31.f, 0.5f);
    unsigned g6 = (unsigned)fmaf(g, 63.f, 0.5f);
    unsigned b5 = (unsigned)fmaf(b, 31.f, 0.5f);
    return (r5 << 11) | (g6 << 5) | b5;
}

// ---- repack: tex[y][x] = uint2{565(y,x)|565(y,x+1)<<16, 565(y+1,x)|565(y+1,x+1)<<16} ----
__global__ __launch_bounds__(256) void repack_quad565(const float* __restrict__ rgb1,
                                                      const float* __restrict__ rgb2,
                                                      uint2* __restrict__ t1,
                                                      uint2* __restrict__ t2) {
    const int gpi = TH_QUAD * (W_IMG / 4);
    int t = blockIdx.x * 256 + threadIdx.x;
    if (t >= 2 * gpi) return;
    const int img = t >= gpi;
    const int g = t - img * gpi;
    const int y = g / (W_IMG / 4);
    const int x = (g - y * (W_IMG / 4)) * 4;
    const float* src = img ? rgb2 : rgb1;
    uint2* dst = img ? t2 : t1;
    unsigned pk[2][5];
#pragma unroll
    for (int r = 0; r < 2; ++r) {
        const int yy = y + r;
        float px[3][5];
#pragma unroll
        for (int c = 0; c < 3; ++c) {
            const float* b = src + (size_t)c * HW_IMG + (size_t)yy * W_IMG + x;
            float4 a = *(const float4*)b;
            float e = (x + 4 < W_IMG) ? b[4] : a.w;
            px[c][0] = a.x; px[c][1] = a.y; px[c][2] = a.z; px[c][3] = a.w; px[c][4] = e;
        }
#pragma unroll
        for (int k = 0; k < 5; ++k) pk[r][k] = quant565(px[0][k], px[1][k], px[2][k]);
    }
    uint2* o = dst + (size_t)y * W_IMG + x;
#pragma unroll
    for (int k = 0; k < 4; ++k)
        o[k] = make_uint2(pk[0][k] | (pk[0][k + 1] << 16), pk[1][k] | (pk[1][k + 1] << 16));
}

// decode 565 quad + bilinear MSE contribution (normalized [0,1] space)
__device__ __forceinline__ float mse565(uint2 qa, uint2 qb, float wxa, float wya, float wxb,
                                        float wyb) {
    float wa00 = (1.f - wxa) * (1.f - wya), wa01 = wxa * (1.f - wya);
    float wa10 = (1.f - wxa) * wya, wa11 = wxa * wya;
    float wb00 = (1.f - wxb) * (1.f - wyb), wb01 = wxb * (1.f - wyb);
    float wb10 = (1.f - wxb) * wyb, wb11 = wxb * wyb;
    unsigned a00 = qa.x & 0xffffu, a01 = qa.x >> 16, a10 = qa.y & 0xffffu, a11 = qa.y >> 16;
    unsigned b00 = qb.x & 0xffffu, b01 = qb.x >> 16, b10 = qb.y & 0xffffu, b11 = qb.y >> 16;
    float ra = fmaf((float)(a00 >> 11), wa00, fmaf((float)(a01 >> 11), wa01,
               fmaf((float)(a10 >> 11), wa10, (float)(a11 >> 11) * wa11)));
    float rb = fmaf((float)(b00 >> 11), wb00, fmaf((float)(b01 >> 11), wb01,
               fmaf((float)(b10 >> 11), wb10, (float)(b11 >> 11) * wb11)));
    float ga = fmaf((float)((a00 >> 5) & 63u), wa00, fmaf((float)((a01 >> 5) & 63u), wa01,
               fmaf((float)((a10 >> 5) & 63u), wa10, (float)((a11 >> 5) & 63u) * wa11)));
    float gb = fmaf((float)((b00 >> 5) & 63u), wb00, fmaf((float)((b01 >> 5) & 63u), wb01,
               fmaf((float)((b10 >> 5) & 63u), wb10, (float)((b11 >> 5) & 63u) * wb11)));
    float ba = fmaf((float)(a00 & 31u), wa00, fmaf((float)(a01 & 31u), wa01,
               fmaf((float)(a10 & 31u), wa10, (float)(a11 & 31u) * wa11)));
    float bb = fmaf((float)(b00 & 31u), wb00, fmaf((float)(b01 & 31u), wb01,
               fmaf((float)(b10 & 31u), wb10, (float)(b11 & 31u) * wb11)));
    float dr = (ra - rb) * (1.f / 31.f);
    float dg = (ga - gb) * (1.f / 63.f);
    float db = (ba - bb) * (1.f / 31.f);
    return fmaf(dr, dr, fmaf(dg, dg, db * db));
}

// ---- sample: persistent waves, NDESC descriptors/iter = 4*NDESC gathers in flight ----
__global__ __launch_bounds__(256) void sample_kernel(
    const float4* __restrict__ geo, const float* __restrict__ K1, const float* __restrict__ T,
    const uint2* __restrict__ im1, const uint2* __restrict__ im2,
    const unsigned* __restrict__ sched, const int* __restrict__ total_p,
    double* __restrict__ part) {
    const int wid = blockIdx.x * 4 + (threadIdx.x >> 6);
    const int lane = threadIdx.x & 63;
    const int nw = gridDim.x * 4;
    const int total = *total_p;

    const float k00 = K1[0], k01 = K1[1], k02 = K1[2];
    const float k10 = K1[3], k11 = K1[4], k12 = K1[5];
    const float k20 = K1[6], k21 = K1[7], k22 = K1[8];
    const float t00 = T[0], t01 = T[1], t02 = T[2], t03 = T[3];
    const float t10 = T[4], t11 = T[5], t12 = T[6], t13 = T[7];
    const float t20 = T[8], t21 = T[9], t22 = T[10], t23 = T[11];

    float lsum = 0.f;
    for (int base = wid; base < total; base += NDESC * nw) {
        int off1[2 * NDESC], off2[2 * NDESC];
        float wx1[2 * NDESC], wy1[2 * NDESC], wx2[2 * NDESC], wy2[2 * NDESC];
        bool ok[2 * NDESC];
#pragma unroll
        for (int d = 0; d < NDESC; ++d) {
            const int idx = base + d * nw;
            const bool has = idx < total;
            const unsigned s =
                has ? (unsigned)__builtin_amdgcn_readfirstlane((int)sched[idx]) : 0u;
            const int e = (int)(s >> 8);
            const int kk = (int)(s & 255u);
            const float4 g0 = geo[3 * e + 0];
            const float4 g1 = geo[3 * e + 1];
            const float4 g2 = geo[3 * e + 2];
            const int ns = __float_as_int(g2.w);
            const float lod = g0.w * __builtin_amdgcn_rcpf(g1.w);  // len/denom
#pragma unroll
            for (int h = 0; h < 2; ++h) {
                const int j = d * 2 + h;
                const int i = kk * 128 + h * 64 + lane;
                ok[j] = has && (i < ns);
                const int ic = min(i, ns - 1);
                int px = ic / NUM_V;
                int dy = ic - px * NUM_V;
                float cx = (float)px * lod;
                float cy = (float)dy * (0.5f / 9.0f);
                float X = fmaf(g1.x, cx, fmaf(g2.x, cy, g0.x));
                float Y = fmaf(g1.y, cx, fmaf(g2.y, cy, g0.y));
                float Z = fmaf(g1.z, cx, fmaf(g2.z, cy, g0.z));
                float iw1 = __builtin_amdgcn_rcpf(fmaf(k20, X, fmaf(k21, Y, k22 * Z)));
                float u1 =
                    fminf(fmaxf(fmaf(k00, X, fmaf(k01, Y, k02 * Z)) * iw1, 0.f), 0.999999f);
                float v1 =
                    fminf(fmaxf(fmaf(k10, X, fmaf(k11, Y, k12 * Z)) * iw1, 0.f), 0.999999f);
                float iw2 = __builtin_amdgcn_rcpf(fmaf(t20, X, fmaf(t21, Y, fmaf(t22, Z, t23))));
                float u2 = fminf(
                    fmaxf(fmaf(t00, X, fmaf(t01, Y, fmaf(t02, Z, t03))) * iw2, 0.f), 0.999999f);
                float v2 = fminf(
                    fmaxf(fmaf(t10, X, fmaf(t11, Y, fmaf(t12, Z, t13))) * iw2, 0.f), 0.999999f);
                float xa = u1 * (float)(W_IMG - 1), ya = v1 * (float)(H_IMG - 1);
                float xb = u2 * (float)(W_IMG - 1), yb = v2 * (float)(H_IMG - 1);
                float fxa = floorf(xa), fya = floorf(ya), fxb = floorf(xb), fyb = floorf(yb);
                off1[j] = (int)fya * W_IMG + (int)fxa;
                off2[j] = (int)fyb * W_IMG + (int)fxb;
                wx1[j] = xa - fxa; wy1[j] = ya - fya;
                wx2[j] = xb - fxb; wy2[j] = yb - fyb;
            }
        }
        // issue all gathers before consuming any
        uint2 q1[2 * NDESC], q2[2 * NDESC];
#pragma unroll
        for (int j = 0; j < 2 * NDESC; ++j) q1[j] = im1[off1[j]];
#pragma unroll
        for (int j = 0; j < 2 * NDESC; ++j) q2[j] = im2[off2[j]];
#pragma unroll
        for (int j = 0; j < 2 * NDESC; ++j) {
            float v = mse565(q1[j], q2[j], wx1[j], wy1[j], wx2[j], wy2[j]);
            lsum += ok[j] ? v : 0.f;
        }
    }
    double dsum = (double)lsum;
#pragma unroll
    for (int off = 32; off > 0; off >>= 1) dsum += __shfl_down(dsum, off);
    if (lane == 0) part[wid] = dsum;
}

// ---- finalize ----
__global__ __launch_bounds__(256) void finalize_kernel(const double* __restrict__ part, int NP,
                                                       const double* __restrict__ gnl,
                                                       const double* __restrict__ gzl,
                                                       const double* __restrict__ gcnt, int N,
                                                       int NW, float* __restrict__ out) {
    __shared__ double s_s[4], s_a[4], s_b[4], s_c[4];
    double s = 0.0, a = 0.0, b = 0.0, c = 0.0;
    for (int i = threadIdx.x; i < NP; i += 256) s += part[i];
    for (int i = threadIdx.x; i < NW; i += 256) {
        a += gnl[i];
        b += gzl[i];
        c += gcnt[i];
    }
#pragma unroll
    for (int off = 32; off > 0; off >>= 1) {
        s += __shfl_down(s, off);
        a += __shfl_down(a, off);
        b += __shfl_down(b, off);
        c += __shfl_down(c, off);
    }
    const int wave = threadIdx.x >> 6;
    if ((threadIdx.x & 63) == 0) {
        s_s[wave] = s; s_a[wave] = a; s_b[wave] = b; s_c[wave] = c;
    }
    __syncthreads();
    if (threadIdx.x == 0) {
        double S = s_s[0] + s_s[1] + s_s[2] + s_s[3];
        double A = s_a[0] + s_a[1] + s_a[2] + s_a[3];
        double B = s_b[0] + s_b[1] + s_b[2] + s_b[3];
        double C = s_c[0] + s_c[1] + s_c[2] + s_c[3];
        out[0] = (float)(S / (C * 3.0));
        out[1] = (float)(A / (double)N * 0.5);
        out[2] = (float)(B / (double)N);
    }
}

extern "C" void kernel_launch(void* const* d_in, const int* in_sizes, int n_in, void* d_out,
                              int out_size, void* d_ws, size_t ws_size, hipStream_t stream) {
    const float* ep = (const float*)d_in[0];
    const float* K1 = (const float*)d_in[1];
    const float* K2 = (const float*)d_in[2];
    const float* E1 = (const float*)d_in[3];
    const float* E2 = (const float*)d_in[4];
    const float* rgb1 = (const float*)d_in[5];
    const float* rgb2 = (const float*)d_in[6];
    float* out = (float*)d_out;
    const int N = in_sizes[0] / 12;

    const int GB = (N + 255) / 256;
    const int NW = GB * 4;
    const int NPART = SAMPLE_BLOCKS * 4;

    char* p = (char*)d_ws;
    auto align256 = [](char* q) { return (char*)(((size_t)q + 255) & ~(size_t)255); };
    float* T = (float*)p;                 p += 256;
    int* total = (int*)p;                 p += 256;
    float4* geo = (float4*)p;             p += (size_t)3 * N * sizeof(float4);
    p = align256(p);
    int* nwv = (int*)p;                   p += (size_t)N * sizeof(int);
    p = align256(p);
    double* part = (double*)p;            p += (size_t)NPART * sizeof(double);
    double* gnl = (double*)p;             p += (size_t)NW * sizeof(double);
    double* gzl = (double*)p;             p += (size_t)NW * sizeof(double);
    double* gcnt = (double*)p;            p += (size_t)NW * sizeof(double);
    p = align256(p);
    unsigned* sched = (unsigned*)p;       p += (size_t)N * MAX_CHUNKS * sizeof(unsigned);
    p = align256(p);
    uint2* img1 = (uint2*)p;
    uint2* img2 = img1 + (size_t)TH_QUAD * W_IMG;

    geom_kernel<<<GB, 256, 0, stream>>>(ep, N, geo, nwv, gnl, gzl, gcnt);
    sched_scan_kernel<<<GB, 256, 0, stream>>>(nwv, N, sched, total, K2, E1, E2, T);
    const int rp_threads = 2 * TH_QUAD * (W_IMG / 4);
    repack_quad565<<<(rp_threads + 255) / 256, 256, 0, stream>>>(rgb1, rgb2, img1, img2);
    sample_kernel<<<SAMPLE_BLOCKS, 256, 0, stream>>>(geo, K1, T, img1, img2, sched, total, part);
    finalize_kernel<<<1, 256, 0, stream>>>(part, NPART, gnl, gzl, gcnt, N, NW, out);
}

// Round 12
// 184.861 us; speedup vs baseline: 1.0081x; 1.0081x over previous
//
#include <hip/hip_runtime.h>
#include <math.h>

#define EPSF 1e-6f
#define NUM_V 10
#define W_IMG 2000
#define H_IMG 1500
#define HW_IMG (W_IMG * H_IMG)
#define TH_QUAD (H_IMG - 1)      // quad-origin rows (y0 <= H-2 always)
#define SAMPLE_BLOCKS 2048       // 8192 waves
#define MAX_CHUNKS 80            // ceil(1000*10/128)=79, margin

__device__ __forceinline__ void cross3(const float a[3], const float b[3], float c[3]) {
    c[0] = a[1] * b[2] - a[2] * b[1];
    c[1] = a[2] * b[0] - a[0] * b[2];
    c[2] = a[0] * b[1] - a[1] * b[0];
}
__device__ __forceinline__ float dot3(const float a[3], const float b[3]) {
    return a[0] * b[0] + a[1] * b[1] + a[2] * b[2];
}
__device__ __forceinline__ float norm3(const float a[3]) {
    return sqrtf(a[0] * a[0] + a[1] * a[1] + a[2] * a[2]);
}

// ---- T = K2h @ E2 @ inv(E1), one thread ----
__device__ void do_init(const float* __restrict__ K2, const float* __restrict__ E1,
                        const float* __restrict__ E2, float* __restrict__ T) {
    double M[4][8];
    for (int i = 0; i < 4; ++i)
        for (int j = 0; j < 4; ++j) {
            M[i][j] = (double)E1[i * 4 + j];
            M[i][j + 4] = (i == j) ? 1.0 : 0.0;
        }
    for (int col = 0; col < 4; ++col) {
        int piv = col;
        double best = fabs(M[col][col]);
        for (int r = col + 1; r < 4; ++r) {
            double v = fabs(M[r][col]);
            if (v > best) { best = v; piv = r; }
        }
        if (piv != col)
            for (int j = 0; j < 8; ++j) {
                double t = M[col][j]; M[col][j] = M[piv][j]; M[piv][j] = t;
            }
        double d = M[col][col];
        for (int j = 0; j < 8; ++j) M[col][j] /= d;
        for (int r = 0; r < 4; ++r) {
            if (r == col) continue;
            double f = M[r][col];
            for (int j = 0; j < 8; ++j) M[r][j] -= f * M[col][j];
        }
    }
    double E[4][4];
    for (int i = 0; i < 4; ++i)
        for (int j = 0; j < 4; ++j) {
            double s = 0.0;
            for (int k = 0; k < 4; ++k) s += (double)E2[i * 4 + k] * M[k][j + 4];
            E[i][j] = s;
        }
    for (int i = 0; i < 4; ++i)
        for (int j = 0; j < 4; ++j) {
            double s = 0.0;
            if (i < 3) {
                for (int k = 0; k < 3; ++k) s += (double)K2[i * 3 + k] * E[k][j];
            } else {
                s = E[3][j];
            }
            T[i * 4 + j] = (float)s;
        }
}

// ---- geom: thread per edge; chunk counts; wave-partial losses ----
__global__ __launch_bounds__(256) void geom_kernel(const float* __restrict__ ep, int N,
                                                   float4* __restrict__ geo,
                                                   int* __restrict__ nwv,
                                                   double* __restrict__ gnl,
                                                   double* __restrict__ gzl,
                                                   double* __restrict__ gcnt) {
    const int e = blockIdx.x * 256 + threadIdx.x;
    float nl = 0.f, zl = 0.f;
    int cn = 0;
    if (e < N) {
        const float4* P4 = (const float4*)(ep + (size_t)e * 12);
        float4 a4 = P4[0], b4 = P4[1], c4 = P4[2];
        float p0[3] = {a4.x, a4.y, a4.z};
        float p1[3] = {a4.w, b4.x, b4.y};
        float p2[3] = {b4.z, b4.w, c4.x};
        float p3[3] = {c4.y, c4.z, c4.w};
        float cd[3] = {p1[0] - p0[0], p1[1] - p0[1], p1[2] - p0[2]};
        float nd[3] = {p3[0] - p1[0], p3[1] - p1[1], p3[2] - p1[2]};
        float pd[3] = {p0[0] - p2[0], p0[1] - p2[1], p0[2] - p2[2]};
        float ce[3] = {cd[0] + EPSF, cd[1] + EPSF, cd[2] + EPSF};
        float clen = norm3(ce);
        float dir[3] = {cd[0] / clen, cd[1] / clen, cd[2] / clen};
        float cnv[3];
        cross3(dir, nd, cnv);
        float n1 = norm3(cnv) + EPSF;
        cnv[0] /= n1; cnv[1] /= n1; cnv[2] /= n1;
        if (cnv[2] > 0.f) { cnv[0] = -cnv[0]; cnv[1] = -cnv[1]; cnv[2] = -cnv[2]; }
        float up[3];
        cross3(cnv, dir, up);
        float n2 = norm3(up) + EPSF;
        up[0] /= n2; up[1] /= n2; up[2] /= n2;
        float pn[3];
        cross3(pd, dir, pn);
        float n3 = norm3(pn) + EPSF;
        pn[0] /= n3; pn[1] /= n3; pn[2] /= n3;
        float obs[3];
        cross3(p0, p1, obs);
        float n4 = norm3(obs) + EPSF;
        obs[0] /= n4; obs[1] /= n4; obs[2] /= n4;
        int nh = (int)floorf(clen / 0.05f);
        nh = max(2, min(1000, nh));
        nl = 1.f - dot3(cnv, pn);
        float snp = fminf(fabsf(dot3(up, obs)), 0.5f);
        zl = 1.f - snp * 2.f;
        int nsamp = nh * NUM_V;
        cn = nsamp;
        geo[3 * e + 0] = make_float4(p0[0], p0[1], p0[2], clen);
        geo[3 * e + 1] = make_float4(dir[0], dir[1], dir[2], (float)(nh - 1));
        geo[3 * e + 2] = make_float4(up[0], up[1], up[2], __int_as_float(nsamp));
        nwv[e] = (nsamp + 127) / 128;  // 128-sample chunks
    }
#pragma unroll
    for (int off = 32; off > 0; off >>= 1) {
        nl += __shfl_down(nl, off);
        zl += __shfl_down(zl, off);
        cn += __shfl_down(cn, off);
    }
    if ((threadIdx.x & 63) == 0) {
        const int w = blockIdx.x * 4 + (threadIdx.x >> 6);
        gnl[w] = (double)nl;
        gzl[w] = (double)zl;
        gcnt[w] = (double)cn;
    }
}

// ---- sched(+scan fused): block redundantly sums base prefix, scans locally, scatters ----
__global__ __launch_bounds__(256) void sched_scan_kernel(
    const int* __restrict__ nwv, int N, unsigned* __restrict__ sched, int* __restrict__ total,
    const float* __restrict__ K2, const float* __restrict__ E1, const float* __restrict__ E2,
    float* __restrict__ T) {
    __shared__ int s_red[256];
    const int b = blockIdx.x;
    const int tid = threadIdx.x;
    if (b == 0 && tid == 0) do_init(K2, E1, E2, T);
    const int lo = b * 256;
    int acc = 0;
    for (int i = tid; i < lo; i += 256) acc += nwv[i];
    s_red[tid] = acc;
    __syncthreads();
    for (int off = 128; off > 0; off >>= 1) {
        if (tid < off) s_red[tid] += s_red[tid + off];
        __syncthreads();
    }
    const int base0 = s_red[0];
    __syncthreads();
    const int e = lo + tid;
    const int mine = (e < N) ? nwv[e] : 0;
    s_red[tid] = mine;
    __syncthreads();
    for (int off = 1; off < 256; off <<= 1) {
        int v = (tid >= off) ? s_red[tid - off] : 0;
        __syncthreads();
        s_red[tid] += v;
        __syncthreads();
    }
    if (e < N) {
        int basee = base0 + (s_red[tid] - mine);
        const unsigned tag = ((unsigned)e) << 8;
        for (int j = 0; j < mine; ++j) sched[basee + j] = tag | (unsigned)j;
    }
    if (b == (int)gridDim.x - 1 && tid == 255) *total = base0 + s_red[255];
}

__device__ __forceinline__ unsigned quant565(float r, float g, float b) {
    unsigned r5 = (unsigned)fmaf(r, 31.f, 0.5f);
    unsigned g6 = (unsigned)fmaf(g, 63.f, 0.5f);
    unsigned b5 = (unsigned)fmaf(b, 31.f, 0.5f);
    return (r5 << 11) | (g6 << 5) | b5;
}

// ---- repack: tex[y][x] = uint2{565(y,x)|565(y,x+1)<<16, 565(y+1,x)|565(y+1,x+1)<<16} ----
__global__ __launch_bounds__(256) void repack_quad565(const float* __restrict__ rgb1,
                                                      const float* __restrict__ rgb2,
                                                      uint2* __restrict__ t1,
                                                      uint2* __restrict__ t2) {
    const int gpi = TH_QUAD * (W_IMG / 4);
    int t = blockIdx.x * 256 + threadIdx.x;
    if (t >= 2 * gpi) return;
    const int img = t >= gpi;
    const int g = t - img * gpi;
    const int y = g / (W_IMG / 4);
    const int x = (g - y * (W_IMG / 4)) * 4;
    const float* src = img ? rgb2 : rgb1;
    uint2* dst = img ? t2 : t1;
    unsigned pk[2][5];
#pragma unroll
    for (int r = 0; r < 2; ++r) {
        const int yy = y + r;
        float px[3][5];
#pragma unroll
        for (int c = 0; c < 3; ++c) {
            const float* b = src + (size_t)c * HW_IMG + (size_t)yy * W_IMG + x;
            float4 a = *(const float4*)b;
            float e = (x + 4 < W_IMG) ? b[4] : a.w;
            px[c][0] = a.x; px[c][1] = a.y; px[c][2] = a.z; px[c][3] = a.w; px[c][4] = e;
        }
#pragma unroll
        for (int k = 0; k < 5; ++k) pk[r][k] = quant565(px[0][k], px[1][k], px[2][k]);
    }
    uint2* o = dst + (size_t)y * W_IMG + x;
#pragma unroll
    for (int k = 0; k < 4; ++k)
        o[k] = make_uint2(pk[0][k] | (pk[0][k + 1] << 16), pk[1][k] | (pk[1][k + 1] << 16));
}

// decode 565 quad + bilinear MSE contribution (normalized [0,1] space)
__device__ __forceinline__ float mse565(uint2 qa, uint2 qb, float wxa, float wya, float wxb,
                                        float wyb) {
    float wa00 = (1.f - wxa) * (1.f - wya), wa01 = wxa * (1.f - wya);
    float wa10 = (1.f - wxa) * wya, wa11 = wxa * wya;
    float wb00 = (1.f - wxb) * (1.f - wyb), wb01 = wxb * (1.f - wyb);
    float wb10 = (1.f - wxb) * wyb, wb11 = wxb * wyb;
    unsigned a00 = qa.x & 0xffffu, a01 = qa.x >> 16, a10 = qa.y & 0xffffu, a11 = qa.y >> 16;
    unsigned b00 = qb.x & 0xffffu, b01 = qb.x >> 16, b10 = qb.y & 0xffffu, b11 = qb.y >> 16;
    float ra = fmaf((float)(a00 >> 11), wa00, fmaf((float)(a01 >> 11), wa01,
               fmaf((float)(a10 >> 11), wa10, (float)(a11 >> 11) * wa11)));
    float rb = fmaf((float)(b00 >> 11), wb00, fmaf((float)(b01 >> 11), wb01,
               fmaf((float)(b10 >> 11), wb10, (float)(b11 >> 11) * wb11)));
    float ga = fmaf((float)((a00 >> 5) & 63u), wa00, fmaf((float)((a01 >> 5) & 63u), wa01,
               fmaf((float)((a10 >> 5) & 63u), wa10, (float)((a11 >> 5) & 63u) * wa11)));
    float gb = fmaf((float)((b00 >> 5) & 63u), wb00, fmaf((float)((b01 >> 5) & 63u), wb01,
               fmaf((float)((b10 >> 5) & 63u), wb10, (float)((b11 >> 5) & 63u) * wb11)));
    float ba = fmaf((float)(a00 & 31u), wa00, fmaf((float)(a01 & 31u), wa01,
               fmaf((float)(a10 & 31u), wa10, (float)(a11 & 31u) * wa11)));
    float bb = fmaf((float)(b00 & 31u), wb00, fmaf((float)(b01 & 31u), wb01,
               fmaf((float)(b10 & 31u), wb10, (float)(b11 & 31u) * wb11)));
    float dr = (ra - rb) * (1.f / 31.f);
    float dg = (ga - gb) * (1.f / 63.f);
    float db = (ba - bb) * (1.f / 31.f);
    return fmaf(dr, dr, fmaf(dg, dg, db * db));
}

// ---- sample: persistent waves, 2 descriptors/iter, fast-rcp projections (no fences) ----
__global__ __launch_bounds__(256) void sample_kernel(
    const float4* __restrict__ geo, const float* __restrict__ K1, const float* __restrict__ T,
    const uint2* __restrict__ im1, const uint2* __restrict__ im2,
    const unsigned* __restrict__ sched, const int* __restrict__ total_p,
    double* __restrict__ part) {
    const int wid = blockIdx.x * 4 + (threadIdx.x >> 6);
    const int lane = threadIdx.x & 63;
    const int nw = gridDim.x * 4;
    const int total = *total_p;

    const float k00 = K1[0], k01 = K1[1], k02 = K1[2];
    const float k10 = K1[3], k11 = K1[4], k12 = K1[5];
    const float k20 = K1[6], k21 = K1[7], k22 = K1[8];
    const float t00 = T[0], t01 = T[1], t02 = T[2], t03 = T[3];
    const float t10 = T[4], t11 = T[5], t12 = T[6], t13 = T[7];
    const float t20 = T[8], t21 = T[9], t22 = T[10], t23 = T[11];

    float lsum = 0.f;
    for (int base = wid; base < total; base += 2 * nw) {
        const int idxB = base + nw;
        const bool has2 = idxB < total;
        const unsigned sA = (unsigned)__builtin_amdgcn_readfirstlane((int)sched[base]);
        const unsigned sB =
            has2 ? (unsigned)__builtin_amdgcn_readfirstlane((int)sched[idxB]) : sA;
        const int eA = (int)(sA >> 8), kA = (int)(sA & 255u);
        const int eB = (int)(sB >> 8), kB = (int)(sB & 255u);
        const float4 a0 = geo[3 * eA + 0], a1 = geo[3 * eA + 1], a2 = geo[3 * eA + 2];
        const float4 b0 = geo[3 * eB + 0], b1 = geo[3 * eB + 1], b2 = geo[3 * eB + 2];
        const int nsA = __float_as_int(a2.w), nsB = __float_as_int(b2.w);
        const float lodA = a0.w * __builtin_amdgcn_rcpf(a1.w);  // len/denom
        const float lodB = b0.w * __builtin_amdgcn_rcpf(b1.w);

        int off1[4], off2[4];
        float wx1[4], wy1[4], wx2[4], wy2[4];
        bool ok[4];
#pragma unroll
        for (int j = 0; j < 4; ++j) {
            const int d = j >> 1, h = j & 1;
            const float4 g0 = d ? b0 : a0;
            const float4 g1 = d ? b1 : a1;
            const float4 g2 = d ? b2 : a2;
            const int ns = d ? nsB : nsA;
            const int kk = d ? kB : kA;
            const float lod = d ? lodB : lodA;
            const int i = kk * 128 + h * 64 + lane;
            ok[j] = (i < ns) && (d == 0 || has2);
            const int ic = min(i, ns - 1);
            int px = ic / NUM_V;
            int dy = ic - px * NUM_V;
            float cx = (float)px * lod;
            float cy = (float)dy * (0.5f / 9.0f);
            float X = fmaf(g1.x, cx, fmaf(g2.x, cy, g0.x));
            float Y = fmaf(g1.y, cx, fmaf(g2.y, cy, g0.y));
            float Z = fmaf(g1.z, cx, fmaf(g2.z, cy, g0.z));
            float iw1 = __builtin_amdgcn_rcpf(fmaf(k20, X, fmaf(k21, Y, k22 * Z)));
            float u1 = fminf(fmaxf(fmaf(k00, X, fmaf(k01, Y, k02 * Z)) * iw1, 0.f), 0.999999f);
            float v1 = fminf(fmaxf(fmaf(k10, X, fmaf(k11, Y, k12 * Z)) * iw1, 0.f), 0.999999f);
            float iw2 = __builtin_amdgcn_rcpf(fmaf(t20, X, fmaf(t21, Y, fmaf(t22, Z, t23))));
            float u2 = fminf(
                fmaxf(fmaf(t00, X, fmaf(t01, Y, fmaf(t02, Z, t03))) * iw2, 0.f), 0.999999f);
            float v2 = fminf(
                fmaxf(fmaf(t10, X, fmaf(t11, Y, fmaf(t12, Z, t13))) * iw2, 0.f), 0.999999f);
            float xa = u1 * (float)(W_IMG - 1), ya = v1 * (float)(H_IMG - 1);
            float xb = u2 * (float)(W_IMG - 1), yb = v2 * (float)(H_IMG - 1);
            float fxa = floorf(xa), fya = floorf(ya), fxb = floorf(xb), fyb = floorf(yb);
            off1[j] = (int)fya * W_IMG + (int)fxa;
            off2[j] = (int)fyb * W_IMG + (int)fxb;
            wx1[j] = xa - fxa; wy1[j] = ya - fya;
            wx2[j] = xb - fxb; wy2[j] = yb - fyb;
        }
        uint2 q1[4], q2[4];
#pragma unroll
        for (int j = 0; j < 4; ++j) q1[j] = im1[off1[j]];
#pragma unroll
        for (int j = 0; j < 4; ++j) q2[j] = im2[off2[j]];
#pragma unroll
        for (int j = 0; j < 4; ++j) {
            float v = mse565(q1[j], q2[j], wx1[j], wy1[j], wx2[j], wy2[j]);
            lsum += ok[j] ? v : 0.f;
        }
    }
    double dsum = (double)lsum;
#pragma unroll
    for (int off = 32; off > 0; off >>= 1) dsum += __shfl_down(dsum, off);
    if (lane == 0) part[wid] = dsum;
}

// ---- finalize ----
__global__ __launch_bounds__(256) void finalize_kernel(const double* __restrict__ part, int NP,
                                                       const double* __restrict__ gnl,
                                                       const double* __restrict__ gzl,
                                                       const double* __restrict__ gcnt, int N,
                                                       int NW, float* __restrict__ out) {
    __shared__ double s_s[4], s_a[4], s_b[4], s_c[4];
    double s = 0.0, a = 0.0, b = 0.0, c = 0.0;
    for (int i = threadIdx.x; i < NP; i += 256) s += part[i];
    for (int i = threadIdx.x; i < NW; i += 256) {
        a += gnl[i];
        b += gzl[i];
        c += gcnt[i];
    }
#pragma unroll
    for (int off = 32; off > 0; off >>= 1) {
        s += __shfl_down(s, off);
        a += __shfl_down(a, off);
        b += __shfl_down(b, off);
        c += __shfl_down(c, off);
    }
    const int wave = threadIdx.x >> 6;
    if ((threadIdx.x & 63) == 0) {
        s_s[wave] = s; s_a[wave] = a; s_b[wave] = b; s_c[wave] = c;
    }
    __syncthreads();
    if (threadIdx.x == 0) {
        double S = s_s[0] + s_s[1] + s_s[2] + s_s[3];
        double A = s_a[0] + s_a[1] + s_a[2] + s_a[3];
        double B = s_b[0] + s_b[1] + s_b[2] + s_b[3];
        double C = s_c[0] + s_c[1] + s_c[2] + s_c[3];
        out[0] = (float)(S / (C * 3.0));
        out[1] = (float)(A / (double)N * 0.5);
        out[2] = (float)(B / (double)N);
    }
}

extern "C" void kernel_launch(void* const* d_in, const int* in_sizes, int n_in, void* d_out,
                              int out_size, void* d_ws, size_t ws_size, hipStream_t stream) {
    const float* ep = (const float*)d_in[0];
    const float* K1 = (const float*)d_in[1];
    const float* K2 = (const float*)d_in[2];
    const float* E1 = (const float*)d_in[3];
    const float* E2 = (const float*)d_in[4];
    const float* rgb1 = (const float*)d_in[5];
    const float* rgb2 = (const float*)d_in[6];
    float* out = (float*)d_out;
    const int N = in_sizes[0] / 12;

    const int GB = (N + 255) / 256;
    const int NW = GB * 4;
    const int NPART = SAMPLE_BLOCKS * 4;

    char* p = (char*)d_ws;
    auto align256 = [](char* q) { return (char*)(((size_t)q + 255) & ~(size_t)255); };
    float* T = (float*)p;                 p += 256;
    int* total = (int*)p;                 p += 256;
    float4* geo = (float4*)p;             p += (size_t)3 * N * sizeof(float4);
    p = align256(p);
    int* nwv = (int*)p;                   p += (size_t)N * sizeof(int);
    p = align256(p);
    double* part = (double*)p;            p += (size_t)NPART * sizeof(double);
    double* gnl = (double*)p;             p += (size_t)NW * sizeof(double);
    double* gzl = (double*)p;             p += (size_t)NW * sizeof(double);
    double* gcnt = (double*)p;            p += (size_t)NW * sizeof(double);
    p = align256(p);
    unsigned* sched = (unsigned*)p;       p += (size_t)N * MAX_CHUNKS * sizeof(unsigned);
    p = align256(p);
    uint2* img1 = (uint2*)p;
    uint2* img2 = img1 + (size_t)TH_QUAD * W_IMG;

    geom_kernel<<<GB, 256, 0, stream>>>(ep, N, geo, nwv, gnl, gzl, gcnt);
    sched_scan_kernel<<<GB, 256, 0, stream>>>(nwv, N, sched, total, K2, E1, E2, T);
    const int rp_threads = 2 * TH_QUAD * (W_IMG / 4);
    repack_quad565<<<(rp_threads + 255) / 256, 256, 0, stream>>>(rgb1, rgb2, img1, img2);
    sample_kernel<<<SAMPLE_BLOCKS, 256, 0, stream>>>(geo, K1, T, img1, img2, sched, total, part);
    finalize_kernel<<<1, 256, 0, stream>>>(part, NPART, gnl, gzl, gcnt, N, NW, out);
}

// Round 13
// 177.596 us; speedup vs baseline: 1.0494x; 1.0409x over previous
//
#include <hip/hip_runtime.h>
#include <math.h>

#define EPSF 1e-6f
#define NUM_V 10
#define W_IMG 2000
#define H_IMG 1500
#define HW_IMG (W_IMG * H_IMG)
#define TH_QUAD (H_IMG - 1)      // quad-origin rows (y0 <= H-2 always)
#define SAMPLE_BLOCKS 2048       // 8192 waves
#define MAX_CHUNKS 80            // ceil(1000*10/128)=79, margin
#define ROW_MARGIN 8             // safety rows around the projected v-bbox

__device__ __forceinline__ void cross3(const float a[3], const float b[3], float c[3]) {
    c[0] = a[1] * b[2] - a[2] * b[1];
    c[1] = a[2] * b[0] - a[0] * b[2];
    c[2] = a[0] * b[1] - a[1] * b[0];
}
__device__ __forceinline__ float dot3(const float a[3], const float b[3]) {
    return a[0] * b[0] + a[1] * b[1] + a[2] * b[2];
}
__device__ __forceinline__ float norm3(const float a[3]) {
    return sqrtf(a[0] * a[0] + a[1] * a[1] + a[2] * a[2]);
}

// ---- T = K2h @ E2 @ inv(E1), one thread ----
__device__ void do_init(const float* __restrict__ K2, const float* __restrict__ E1,
                        const float* __restrict__ E2, float* __restrict__ T) {
    double M[4][8];
    for (int i = 0; i < 4; ++i)
        for (int j = 0; j < 4; ++j) {
            M[i][j] = (double)E1[i * 4 + j];
            M[i][j + 4] = (i == j) ? 1.0 : 0.0;
        }
    for (int col = 0; col < 4; ++col) {
        int piv = col;
        double best = fabs(M[col][col]);
        for (int r = col + 1; r < 4; ++r) {
            double v = fabs(M[r][col]);
            if (v > best) { best = v; piv = r; }
        }
        if (piv != col)
            for (int j = 0; j < 8; ++j) {
                double t = M[col][j]; M[col][j] = M[piv][j]; M[piv][j] = t;
            }
        double d = M[col][col];
        for (int j = 0; j < 8; ++j) M[col][j] /= d;
        for (int r = 0; r < 4; ++r) {
            if (r == col) continue;
            double f = M[r][col];
            for (int j = 0; j < 8; ++j) M[r][j] -= f * M[col][j];
        }
    }
    double E[4][4];
    for (int i = 0; i < 4; ++i)
        for (int j = 0; j < 4; ++j) {
            double s = 0.0;
            for (int k = 0; k < 4; ++k) s += (double)E2[i * 4 + k] * M[k][j + 4];
            E[i][j] = s;
        }
    for (int i = 0; i < 4; ++i)
        for (int j = 0; j < 4; ++j) {
            double s = 0.0;
            if (i < 3) {
                for (int k = 0; k < 3; ++k) s += (double)K2[i * 3 + k] * E[k][j];
            } else {
                s = E[3][j];
            }
            T[i * 4 + j] = (float)s;
        }
}

// ---- init: T matrix + bbox sentinels (runs before geom) ----
__global__ void init_kernel(const float* __restrict__ K2, const float* __restrict__ E1,
                            const float* __restrict__ E2, float* __restrict__ T,
                            int* __restrict__ bbox) {
    if (threadIdx.x != 0) return;
    do_init(K2, E1, E2, T);
    bbox[0] = 0x7fffffff;   // ymin img1 (quad rows)
    bbox[1] = -0x7fffffff;  // ymax img1
    bbox[2] = 0x7fffffff;   // ymin img2
    bbox[3] = -0x7fffffff;  // ymax img2
}

// ---- geom: thread per edge; chunk counts; wave-partial losses; v-row bbox ----
__global__ __launch_bounds__(256) void geom_kernel(const float* __restrict__ ep, int N,
                                                   const float* __restrict__ K1,
                                                   const float* __restrict__ T,
                                                   float4* __restrict__ geo,
                                                   int* __restrict__ nwv,
                                                   double* __restrict__ gnl,
                                                   double* __restrict__ gzl,
                                                   double* __restrict__ gcnt,
                                                   int* __restrict__ bbox) {
    const int e = blockIdx.x * 256 + threadIdx.x;
    float nl = 0.f, zl = 0.f;
    int cn = 0;
    int r1min = 0x7fffffff, r1max = -0x7fffffff;
    int r2min = 0x7fffffff, r2max = -0x7fffffff;
    if (e < N) {
        const float4* P4 = (const float4*)(ep + (size_t)e * 12);
        float4 a4 = P4[0], b4 = P4[1], c4 = P4[2];
        float p0[3] = {a4.x, a4.y, a4.z};
        float p1[3] = {a4.w, b4.x, b4.y};
        float p2[3] = {b4.z, b4.w, c4.x};
        float p3[3] = {c4.y, c4.z, c4.w};
        float cd[3] = {p1[0] - p0[0], p1[1] - p0[1], p1[2] - p0[2]};
        float nd[3] = {p3[0] - p1[0], p3[1] - p1[1], p3[2] - p1[2]};
        float pd[3] = {p0[0] - p2[0], p0[1] - p2[1], p0[2] - p2[2]};
        float ce[3] = {cd[0] + EPSF, cd[1] + EPSF, cd[2] + EPSF};
        float clen = norm3(ce);
        float dir[3] = {cd[0] / clen, cd[1] / clen, cd[2] / clen};
        float cnv[3];
        cross3(dir, nd, cnv);
        float n1 = norm3(cnv) + EPSF;
        cnv[0] /= n1; cnv[1] /= n1; cnv[2] /= n1;
        if (cnv[2] > 0.f) { cnv[0] = -cnv[0]; cnv[1] = -cnv[1]; cnv[2] = -cnv[2]; }
        float up[3];
        cross3(cnv, dir, up);
        float n2 = norm3(up) + EPSF;
        up[0] /= n2; up[1] /= n2; up[2] /= n2;
        float pn[3];
        cross3(pd, dir, pn);
        float n3 = norm3(pn) + EPSF;
        pn[0] /= n3; pn[1] /= n3; pn[2] /= n3;
        float obs[3];
        cross3(p0, p1, obs);
        float n4 = norm3(obs) + EPSF;
        obs[0] /= n4; obs[1] /= n4; obs[2] /= n4;
        int nh = (int)floorf(clen / 0.05f);
        nh = max(2, min(1000, nh));
        nl = 1.f - dot3(cnv, pn);
        float snp = fminf(fabsf(dot3(up, obs)), 0.5f);
        zl = 1.f - snp * 2.f;
        int nsamp = nh * NUM_V;
        cn = nsamp;
        geo[3 * e + 0] = make_float4(p0[0], p0[1], p0[2], clen);
        geo[3 * e + 1] = make_float4(dir[0], dir[1], dir[2], (float)(nh - 1));
        geo[3 * e + 2] = make_float4(up[0], up[1], up[2], __int_as_float(nsamp));
        nwv[e] = (nsamp + 127) / 128;

        // v-row bbox over the sample rectangle: extremes at the 4 corners (Mobius map)
        const float k10 = K1[3], k11 = K1[4], k12 = K1[5];
        const float k20 = K1[6], k21 = K1[7], k22 = K1[8];
        const float t10 = T[4], t11 = T[5], t12 = T[6], t13 = T[7];
        const float t20 = T[8], t21 = T[9], t22 = T[10], t23 = T[11];
        float v1min = 1e9f, v1max = -1e9f, v2min = 1e9f, v2max = -1e9f;
#pragma unroll
        for (int c = 0; c < 4; ++c) {
            float cx = (c & 1) ? clen : 0.f;
            float cy = (c & 2) ? 0.5f : 0.f;
            float X = fmaf(dir[0], cx, fmaf(up[0], cy, p0[0]));
            float Y = fmaf(dir[1], cx, fmaf(up[1], cy, p0[1]));
            float Z = fmaf(dir[2], cx, fmaf(up[2], cy, p0[2]));
            float iw1 = __builtin_amdgcn_rcpf(fmaf(k20, X, fmaf(k21, Y, k22 * Z)));
            float v1 = fminf(fmaxf(fmaf(k10, X, fmaf(k11, Y, k12 * Z)) * iw1, 0.f), 0.999999f);
            float iw2 = __builtin_amdgcn_rcpf(fmaf(t20, X, fmaf(t21, Y, fmaf(t22, Z, t23))));
            float v2 = fminf(
                fmaxf(fmaf(t10, X, fmaf(t11, Y, fmaf(t12, Z, t13))) * iw2, 0.f), 0.999999f);
            v1min = fminf(v1min, v1); v1max = fmaxf(v1max, v1);
            v2min = fminf(v2min, v2); v2max = fmaxf(v2max, v2);
        }
        r1min = (int)floorf(v1min * (float)(H_IMG - 1)) - ROW_MARGIN;
        r1max = (int)floorf(v1max * (float)(H_IMG - 1)) + ROW_MARGIN;
        r2min = (int)floorf(v2min * (float)(H_IMG - 1)) - ROW_MARGIN;
        r2max = (int)floorf(v2max * (float)(H_IMG - 1)) + ROW_MARGIN;
    }
#pragma unroll
    for (int off = 32; off > 0; off >>= 1) {
        nl += __shfl_down(nl, off);
        zl += __shfl_down(zl, off);
        cn += __shfl_down(cn, off);
        r1min = min(r1min, __shfl_down(r1min, off));
        r1max = max(r1max, __shfl_down(r1max, off));
        r2min = min(r2min, __shfl_down(r2min, off));
        r2max = max(r2max, __shfl_down(r2max, off));
    }
    __shared__ int s_bb[4][4];
    const int wave = threadIdx.x >> 6;
    if ((threadIdx.x & 63) == 0) {
        const int w = blockIdx.x * 4 + wave;
        gnl[w] = (double)nl;
        gzl[w] = (double)zl;
        gcnt[w] = (double)cn;
        s_bb[wave][0] = r1min; s_bb[wave][1] = r1max;
        s_bb[wave][2] = r2min; s_bb[wave][3] = r2max;
    }
    __syncthreads();
    if (threadIdx.x == 0) {
        int m0 = min(min(s_bb[0][0], s_bb[1][0]), min(s_bb[2][0], s_bb[3][0]));
        int m1 = max(max(s_bb[0][1], s_bb[1][1]), max(s_bb[2][1], s_bb[3][1]));
        int m2 = min(min(s_bb[0][2], s_bb[1][2]), min(s_bb[2][2], s_bb[3][2]));
        int m3 = max(max(s_bb[0][3], s_bb[1][3]), max(s_bb[2][3], s_bb[3][3]));
        atomicMin(&bbox[0], m0);
        atomicMax(&bbox[1], m1);
        atomicMin(&bbox[2], m2);
        atomicMax(&bbox[3], m3);
    }
}

// ---- sched(+scan fused): block redundantly sums base prefix, scans locally, scatters ----
__global__ __launch_bounds__(256) void sched_scan_kernel(const int* __restrict__ nwv, int N,
                                                         unsigned* __restrict__ sched,
                                                         int* __restrict__ total) {
    __shared__ int s_red[256];
    const int b = blockIdx.x;
    const int tid = threadIdx.x;
    const int lo = b * 256;
    int acc = 0;
    for (int i = tid; i < lo; i += 256) acc += nwv[i];
    s_red[tid] = acc;
    __syncthreads();
    for (int off = 128; off > 0; off >>= 1) {
        if (tid < off) s_red[tid] += s_red[tid + off];
        __syncthreads();
    }
    const int base0 = s_red[0];
    __syncthreads();
    const int e = lo + tid;
    const int mine = (e < N) ? nwv[e] : 0;
    s_red[tid] = mine;
    __syncthreads();
    for (int off = 1; off < 256; off <<= 1) {
        int v = (tid >= off) ? s_red[tid - off] : 0;
        __syncthreads();
        s_red[tid] += v;
        __syncthreads();
    }
    if (e < N) {
        int basee = base0 + (s_red[tid] - mine);
        const unsigned tag = ((unsigned)e) << 8;
        for (int j = 0; j < mine; ++j) sched[basee + j] = tag | (unsigned)j;
    }
    if (b == (int)gridDim.x - 1 && tid == 255) *total = base0 + s_red[255];
}

__device__ __forceinline__ unsigned quant565(float r, float g, float b) {
    unsigned r5 = (unsigned)fmaf(r, 31.f, 0.5f);
    unsigned g6 = (unsigned)fmaf(g, 63.f, 0.5f);
    unsigned b5 = (unsigned)fmaf(b, 31.f, 0.5f);
    return (r5 << 11) | (g6 << 5) | b5;
}

// ---- repack: only quad-rows inside the projected v-bbox; uint4 stores ----
__global__ __launch_bounds__(256) void repack_quad565(const float* __restrict__ rgb1,
                                                      const float* __restrict__ rgb2,
                                                      uint2* __restrict__ t1,
                                                      uint2* __restrict__ t2,
                                                      const int* __restrict__ bbox) {
    const int gpi = TH_QUAD * (W_IMG / 4);
    int t = blockIdx.x * 256 + threadIdx.x;
    if (t >= 2 * gpi) return;
    const int img = t >= gpi;
    const int g = t - img * gpi;
    const int y = g / (W_IMG / 4);
    const int bmin = max(0, bbox[img * 2]);
    const int bmax = min(TH_QUAD - 1, bbox[img * 2 + 1]);
    if (y < bmin || y > bmax) return;  // row never sampled
    const int x = (g - y * (W_IMG / 4)) * 4;
    const float* src = img ? rgb2 : rgb1;
    uint2* dst = img ? t2 : t1;
    unsigned pk[2][5];
#pragma unroll
    for (int r = 0; r < 2; ++r) {
        const int yy = y + r;
        float px[3][5];
#pragma unroll
        for (int c = 0; c < 3; ++c) {
            const float* b = src + (size_t)c * HW_IMG + (size_t)yy * W_IMG + x;
            float4 a = *(const float4*)b;
            float e = (x + 4 < W_IMG) ? b[4] : a.w;
            px[c][0] = a.x; px[c][1] = a.y; px[c][2] = a.z; px[c][3] = a.w; px[c][4] = e;
        }
#pragma unroll
        for (int k = 0; k < 5; ++k) pk[r][k] = quant565(px[0][k], px[1][k], px[2][k]);
    }
    uint2* o = dst + (size_t)y * W_IMG + x;
    uint4 s0 = make_uint4(pk[0][0] | (pk[0][1] << 16), pk[1][0] | (pk[1][1] << 16),
                          pk[0][1] | (pk[0][2] << 16), pk[1][1] | (pk[1][2] << 16));
    uint4 s1 = make_uint4(pk[0][2] | (pk[0][3] << 16), pk[1][2] | (pk[1][3] << 16),
                          pk[0][3] | (pk[0][4] << 16), pk[1][3] | (pk[1][4] << 16));
    *(uint4*)(o + 0) = s0;
    *(uint4*)(o + 2) = s1;
}

// decode 565 quad + bilinear MSE contribution (normalized [0,1] space)
__device__ __forceinline__ float mse565(uint2 qa, uint2 qb, float wxa, float wya, float wxb,
                                        float wyb) {
    float wa00 = (1.f - wxa) * (1.f - wya), wa01 = wxa * (1.f - wya);
    float wa10 = (1.f - wxa) * wya, wa11 = wxa * wya;
    float wb00 = (1.f - wxb) * (1.f - wyb), wb01 = wxb * (1.f - wyb);
    float wb10 = (1.f - wxb) * wyb, wb11 = wxb * wyb;
    unsigned a00 = qa.x & 0xffffu, a01 = qa.x >> 16, a10 = qa.y & 0xffffu, a11 = qa.y >> 16;
    unsigned b00 = qb.x & 0xffffu, b01 = qb.x >> 16, b10 = qb.y & 0xffffu, b11 = qb.y >> 16;
    float ra = fmaf((float)(a00 >> 11), wa00, fmaf((float)(a01 >> 11), wa01,
               fmaf((float)(a10 >> 11), wa10, (float)(a11 >> 11) * wa11)));
    float rb = fmaf((float)(b00 >> 11), wb00, fmaf((float)(b01 >> 11), wb01,
               fmaf((float)(b10 >> 11), wb10, (float)(b11 >> 11) * wb11)));
    float ga = fmaf((float)((a00 >> 5) & 63u), wa00, fmaf((float)((a01 >> 5) & 63u), wa01,
               fmaf((float)((a10 >> 5) & 63u), wa10, (float)((a11 >> 5) & 63u) * wa11)));
    float gb = fmaf((float)((b00 >> 5) & 63u), wb00, fmaf((float)((b01 >> 5) & 63u), wb01,
               fmaf((float)((b10 >> 5) & 63u), wb10, (float)((b11 >> 5) & 63u) * wb11)));
    float ba = fmaf((float)(a00 & 31u), wa00, fmaf((float)(a01 & 31u), wa01,
               fmaf((float)(a10 & 31u), wa10, (float)(a11 & 31u) * wa11)));
    float bb = fmaf((float)(b00 & 31u), wb00, fmaf((float)(b01 & 31u), wb01,
               fmaf((float)(b10 & 31u), wb10, (float)(b11 & 31u) * wb11)));
    float dr = (ra - rb) * (1.f / 31.f);
    float dg = (ga - gb) * (1.f / 63.f);
    float db = (ba - bb) * (1.f / 31.f);
    return fmaf(dr, dr, fmaf(dg, dg, db * db));
}

// ---- sample: persistent waves, 2 descriptors/iter, fast-rcp projections (unchanged) ----
__global__ __launch_bounds__(256) void sample_kernel(
    const float4* __restrict__ geo, const float* __restrict__ K1, const float* __restrict__ T,
    const uint2* __restrict__ im1, const uint2* __restrict__ im2,
    const unsigned* __restrict__ sched, const int* __restrict__ total_p,
    double* __restrict__ part) {
    const int wid = blockIdx.x * 4 + (threadIdx.x >> 6);
    const int lane = threadIdx.x & 63;
    const int nw = gridDim.x * 4;
    const int total = *total_p;

    const float k00 = K1[0], k01 = K1[1], k02 = K1[2];
    const float k10 = K1[3], k11 = K1[4], k12 = K1[5];
    const float k20 = K1[6], k21 = K1[7], k22 = K1[8];
    const float t00 = T[0], t01 = T[1], t02 = T[2], t03 = T[3];
    const float t10 = T[4], t11 = T[5], t12 = T[6], t13 = T[7];
    const float t20 = T[8], t21 = T[9], t22 = T[10], t23 = T[11];

    float lsum = 0.f;
    for (int base = wid; base < total; base += 2 * nw) {
        const int idxB = base + nw;
        const bool has2 = idxB < total;
        const unsigned sA = (unsigned)__builtin_amdgcn_readfirstlane((int)sched[base]);
        const unsigned sB =
            has2 ? (unsigned)__builtin_amdgcn_readfirstlane((int)sched[idxB]) : sA;
        const int eA = (int)(sA >> 8), kA = (int)(sA & 255u);
        const int eB = (int)(sB >> 8), kB = (int)(sB & 255u);
        const float4 a0 = geo[3 * eA + 0], a1 = geo[3 * eA + 1], a2 = geo[3 * eA + 2];
        const float4 b0 = geo[3 * eB + 0], b1 = geo[3 * eB + 1], b2 = geo[3 * eB + 2];
        const int nsA = __float_as_int(a2.w), nsB = __float_as_int(b2.w);
        const float lodA = a0.w * __builtin_amdgcn_rcpf(a1.w);  // len/denom
        const float lodB = b0.w * __builtin_amdgcn_rcpf(b1.w);

        int off1[4], off2[4];
        float wx1[4], wy1[4], wx2[4], wy2[4];
        bool ok[4];
#pragma unroll
        for (int j = 0; j < 4; ++j) {
            const int d = j >> 1, h = j & 1;
            const float4 g0 = d ? b0 : a0;
            const float4 g1 = d ? b1 : a1;
            const float4 g2 = d ? b2 : a2;
            const int ns = d ? nsB : nsA;
            const int kk = d ? kB : kA;
            const float lod = d ? lodB : lodA;
            const int i = kk * 128 + h * 64 + lane;
            ok[j] = (i < ns) && (d == 0 || has2);
            const int ic = min(i, ns - 1);
            int px = ic / NUM_V;
            int dy = ic - px * NUM_V;
            float cx = (float)px * lod;
            float cy = (float)dy * (0.5f / 9.0f);
            float X = fmaf(g1.x, cx, fmaf(g2.x, cy, g0.x));
            float Y = fmaf(g1.y, cx, fmaf(g2.y, cy, g0.y));
            float Z = fmaf(g1.z, cx, fmaf(g2.z, cy, g0.z));
            float iw1 = __builtin_amdgcn_rcpf(fmaf(k20, X, fmaf(k21, Y, k22 * Z)));
            float u1 = fminf(fmaxf(fmaf(k00, X, fmaf(k01, Y, k02 * Z)) * iw1, 0.f), 0.999999f);
            float v1 = fminf(fmaxf(fmaf(k10, X, fmaf(k11, Y, k12 * Z)) * iw1, 0.f), 0.999999f);
            float iw2 = __builtin_amdgcn_rcpf(fmaf(t20, X, fmaf(t21, Y, fmaf(t22, Z, t23))));
            float u2 = fminf(
                fmaxf(fmaf(t00, X, fmaf(t01, Y, fmaf(t02, Z, t03))) * iw2, 0.f), 0.999999f);
            float v2 = fminf(
                fmaxf(fmaf(t10, X, fmaf(t11, Y, fmaf(t12, Z, t13))) * iw2, 0.f), 0.999999f);
            float xa = u1 * (float)(W_IMG - 1), ya = v1 * (float)(H_IMG - 1);
            float xb = u2 * (float)(W_IMG - 1), yb = v2 * (float)(H_IMG - 1);
            float fxa = floorf(xa), fya = floorf(ya), fxb = floorf(xb), fyb = floorf(yb);
            off1[j] = (int)fya * W_IMG + (int)fxa;
            off2[j] = (int)fyb * W_IMG + (int)fxb;
            wx1[j] = xa - fxa; wy1[j] = ya - fya;
            wx2[j] = xb - fxb; wy2[j] = yb - fyb;
        }
        uint2 q1[4], q2[4];
#pragma unroll
        for (int j = 0; j < 4; ++j) q1[j] = im1[off1[j]];
#pragma unroll
        for (int j = 0; j < 4; ++j) q2[j] = im2[off2[j]];
#pragma unroll
        for (int j = 0; j < 4; ++j) {
            float v = mse565(q1[j], q2[j], wx1[j], wy1[j], wx2[j], wy2[j]);
            lsum += ok[j] ? v : 0.f;
        }
    }
    double dsum = (double)lsum;
#pragma unroll
    for (int off = 32; off > 0; off >>= 1) dsum += __shfl_down(dsum, off);
    if (lane == 0) part[wid] = dsum;
}

// ---- finalize ----
__global__ __launch_bounds__(256) void finalize_kernel(const double* __restrict__ part, int NP,
                                                       const double* __restrict__ gnl,
                                                       const double* __restrict__ gzl,
                                                       const double* __restrict__ gcnt, int N,
                                                       int NW, float* __restrict__ out) {
    __shared__ double s_s[4], s_a[4], s_b[4], s_c[4];
    double s = 0.0, a = 0.0, b = 0.0, c = 0.0;
    for (int i = threadIdx.x; i < NP; i += 256) s += part[i];
    for (int i = threadIdx.x; i < NW; i += 256) {
        a += gnl[i];
        b += gzl[i];
        c += gcnt[i];
    }
#pragma unroll
    for (int off = 32; off > 0; off >>= 1) {
        s += __shfl_down(s, off);
        a += __shfl_down(a, off);
        b += __shfl_down(b, off);
        c += __shfl_down(c, off);
    }
    const int wave = threadIdx.x >> 6;
    if ((threadIdx.x & 63) == 0) {
        s_s[wave] = s; s_a[wave] = a; s_b[wave] = b; s_c[wave] = c;
    }
    __syncthreads();
    if (threadIdx.x == 0) {
        double S = s_s[0] + s_s[1] + s_s[2] + s_s[3];
        double A = s_a[0] + s_a[1] + s_a[2] + s_a[3];
        double B = s_b[0] + s_b[1] + s_b[2] + s_b[3];
        double C = s_c[0] + s_c[1] + s_c[2] + s_c[3];
        out[0] = (float)(S / (C * 3.0));
        out[1] = (float)(A / (double)N * 0.5);
        out[2] = (float)(B / (double)N);
    }
}

extern "C" void kernel_launch(void* const* d_in, const int* in_sizes, int n_in, void* d_out,
                              int out_size, void* d_ws, size_t ws_size, hipStream_t stream) {
    const float* ep = (const float*)d_in[0];
    const float* K1 = (const float*)d_in[1];
    const float* K2 = (const float*)d_in[2];
    const float* E1 = (const float*)d_in[3];
    const float* E2 = (const float*)d_in[4];
    const float* rgb1 = (const float*)d_in[5];
    const float* rgb2 = (const float*)d_in[6];
    float* out = (float*)d_out;
    const int N = in_sizes[0] / 12;

    const int GB = (N + 255) / 256;
    const int NW = GB * 4;
    const int NPART = SAMPLE_BLOCKS * 4;

    char* p = (char*)d_ws;
    auto align256 = [](char* q) { return (char*)(((size_t)q + 255) & ~(size_t)255); };
    float* T = (float*)p;                 p += 256;
    int* total = (int*)p;                 p += 128;
    int* bbox = (int*)p;                  p += 128;
    float4* geo = (float4*)p;             p += (size_t)3 * N * sizeof(float4);
    p = align256(p);
    int* nwv = (int*)p;                   p += (size_t)N * sizeof(int);
    p = align256(p);
    double* part = (double*)p;            p += (size_t)NPART * sizeof(double);
    double* gnl = (double*)p;             p += (size_t)NW * sizeof(double);
    double* gzl = (double*)p;             p += (size_t)NW * sizeof(double);
    double* gcnt = (double*)p;            p += (size_t)NW * sizeof(double);
    p = align256(p);
    unsigned* sched = (unsigned*)p;       p += (size_t)N * MAX_CHUNKS * sizeof(unsigned);
    p = align256(p);
    uint2* img1 = (uint2*)p;
    uint2* img2 = img1 + (size_t)TH_QUAD * W_IMG;

    init_kernel<<<1, 64, 0, stream>>>(K2, E1, E2, T, bbox);
    geom_kernel<<<GB, 256, 0, stream>>>(ep, N, K1, T, geo, nwv, gnl, gzl, gcnt, bbox);
    sched_scan_kernel<<<GB, 256, 0, stream>>>(nwv, N, sched, total);
    const int rp_threads = 2 * TH_QUAD * (W_IMG / 4);
    repack_quad565<<<(rp_threads + 255) / 256, 256, 0, stream>>>(rgb1, rgb2, img1, img2, bbox);
    sample_kernel<<<SAMPLE_BLOCKS, 256, 0, stream>>>(geo, K1, T, img1, img2, sched, total, part);
    finalize_kernel<<<1, 256, 0, stream>>>(part, NPART, gnl, gzl, gcnt, N, NW, out);
}